// Round 1
// baseline (233.520 us; speedup 1.0000x reference)
//
#include <hip/hip_runtime.h>
#include <hip/hip_bf16.h>
#include <math.h>

#define MM 8192
#define CC 4096
#define DD 768
#define EPSF 1e-8f

#define BM 128
#define BN 128
#define BK 64
#define SPLITC 4
#define TPB 512

// ws layout (floats):
//   [0,      MM)            s_text
//   [MM,     2MM)           t_text
//   [2MM,    2MM+CC)        s_lab
//   [2MM+CC, 2MM+2CC)       t_lab
//   [POS_OFF, POS_OFF+MM)   pos_dist
//   [PART_OFF, ...)         partial top2  [row][SPLITC][2]
#define SOFF_T 0
#define TOFF_T (MM)
#define SOFF_L (2*MM)
#define TOFF_L (2*MM + CC)
#define POS_OFF (2*MM + 2*CC)
#define PART_OFF (POS_OFF + MM)

typedef __attribute__((ext_vector_type(8))) short short8;
typedef __attribute__((ext_vector_type(8))) unsigned short u16x8;
typedef __attribute__((ext_vector_type(4))) float f32x4;

__device__ inline unsigned short f2bf(float f) {
    unsigned int u = __float_as_uint(f);
    u += 0x7FFF + ((u >> 16) & 1);   // round-to-nearest-even
    return (unsigned short)(u >> 16);
}

// ---------------- prep: per-row s (scale) and t (time) ----------------
__global__ void prep_kernel(const float* __restrict__ X, const float* __restrict__ Y,
                            const float* curv_log, const float* ta_log, const float* la_log,
                            float* __restrict__ ws) {
    int wid = threadIdx.x >> 6, lane = threadIdx.x & 63;
    int row = blockIdx.x * 4 + wid;
    float curv = __expf(curv_log[0]);
    const float* base;
    float alpha;
    float* s_out;
    float* t_out;
    int idx;
    if (row < MM) {
        base = X + (size_t)row * DD; alpha = __expf(ta_log[0]);
        s_out = ws + SOFF_T; t_out = ws + TOFF_T; idx = row;
    } else {
        int r = row - MM;
        base = Y + (size_t)r * DD; alpha = __expf(la_log[0]);
        s_out = ws + SOFF_L; t_out = ws + TOFF_L; idx = r;
    }
    float n2 = 0.f;
    #pragma unroll
    for (int t = 0; t < DD / 64; ++t) {
        float v = base[lane + 64 * t];
        n2 += v * v;
    }
    #pragma unroll
    for (int m = 32; m; m >>= 1) n2 += __shfl_xor(n2, m);
    if (lane == 0) {
        float r = sqrtf(curv) * alpha * sqrtf(n2);
        float s = alpha * sinhf(r) / fmaxf(r, EPSF);
        float tt = sqrtf(1.0f / curv + s * s * n2);
        s_out[idx] = s;
        t_out[idx] = tt;
    }
}

// ---------------- pos: exact fp32 positive distance per row ----------------
__global__ void pos_kernel(const float* __restrict__ X, const float* __restrict__ Y,
                           const int* __restrict__ tgt, const float* curv_log,
                           float* __restrict__ ws) {
    int wid = threadIdx.x >> 6, lane = threadIdx.x & 63;
    int row = blockIdx.x * 4 + wid;
    if (row >= MM) return;
    float curv = __expf(curv_log[0]);
    int t = tgt[row];
    const float* xr = X + (size_t)row * DD;
    const float* yr = Y + (size_t)t * DD;
    float dot = 0.f;
    #pragma unroll
    for (int k = 0; k < DD / 64; ++k) dot += xr[lane + 64 * k] * yr[lane + 64 * k];
    #pragma unroll
    for (int m = 32; m; m >>= 1) dot += __shfl_xor(dot, m);
    if (lane == 0) {
        float inner = ws[SOFF_T + row] * ws[SOFF_L + t] * dot - ws[TOFF_T + row] * ws[TOFF_L + t];
        float cd = fmaxf(-curv * inner, 1.0f + EPSF);
        float d = __logf(cd + sqrtf(cd * cd - 1.0f)) * rsqrtf(curv);
        ws[POS_OFF + row] = d;
    }
}

// ---------------- main: fused bf16 MFMA GEMM + arccosh + running top-2 min ----------------
__global__ __launch_bounds__(TPB, 2) void main_kernel(
    const float* __restrict__ X, const float* __restrict__ Y,
    const int* __restrict__ tgt, const float* __restrict__ curv_log,
    float* __restrict__ ws)
{
    // LDS: [kg][row][8] bf16, kg = k/8 within the BK=64 slab
    __shared__ unsigned short Ald[8 * 128 * 8];
    __shared__ unsigned short Bld[8 * 128 * 8];
    __shared__ float red[128][2][2];

    int tid = threadIdx.x;
    int lane = tid & 63, wid = tid >> 6;
    int wr = wid >> 1, wc = wid & 1;          // 4 row-groups x 2 col-groups of waves
    int rb = blockIdx.x >> 2, split = blockIdx.x & 3;
    int rowbase = rb * BM;
    float curv = __expf(curv_log[0]);
    float rsc = rsqrtf(curv);

    const float* s_t = ws + SOFF_T;
    const float* t_t = ws + TOFF_T;
    const float* s_l = ws + SOFF_L;
    const float* t_l = ws + TOFF_L;
    float* part = ws + PART_OFF;

    int rgrp = lane >> 4;
    // rows this lane owns in the C/D fragment layout: row = 32*wr + rf*16 + rgrp*4 + r
    float sa[8], ta[8];
    int tg[8];
    #pragma unroll
    for (int rf = 0; rf < 2; ++rf)
        #pragma unroll
        for (int r = 0; r < 4; ++r) {
            int row = rowbase + 32 * wr + rf * 16 + rgrp * 4 + r;
            sa[rf * 4 + r] = s_t[row];
            ta[rf * 4 + r] = t_t[row];
            tg[rf * 4 + r] = tgt[row];
        }

    float m1[8], m2[8];
    #pragma unroll
    for (int i = 0; i < 8; ++i) { m1[i] = 1e30f; m2[i] = 1e30f; }

    int arow = tid >> 2, kq = tid & 3;   // staging: thread -> (row, 16-float k-chunk)

    for (int jt = 0; jt < (CC / SPLITC) / BN; ++jt) {
        int colbase = split * (CC / SPLITC) + jt * BN;
        f32x4 acc[2][4];
        #pragma unroll
        for (int a = 0; a < 2; ++a)
            #pragma unroll
            for (int b = 0; b < 4; ++b)
                acc[a][b] = (f32x4){0.f, 0.f, 0.f, 0.f};

        for (int ks = 0; ks < DD / BK; ++ks) {
            int k0 = ks * BK;
            const float4* xa = (const float4*)(X + (size_t)(rowbase + arow) * DD + k0 + kq * 16);
            const float4* yb = (const float4*)(Y + (size_t)(colbase + arow) * DD + k0 + kq * 16);
            float4 a0 = xa[0], a1 = xa[1], a2 = xa[2], a3 = xa[3];
            float4 b0 = yb[0], b1 = yb[1], b2 = yb[2], b3 = yb[3];
            __syncthreads();   // previous iter's frag reads done before overwrite
            {
                u16x8 w;
                w[0] = f2bf(a0.x); w[1] = f2bf(a0.y); w[2] = f2bf(a0.z); w[3] = f2bf(a0.w);
                w[4] = f2bf(a1.x); w[5] = f2bf(a1.y); w[6] = f2bf(a1.z); w[7] = f2bf(a1.w);
                *(u16x8*)&Ald[(kq * 2) * 1024 + arow * 8] = w;
                w[0] = f2bf(a2.x); w[1] = f2bf(a2.y); w[2] = f2bf(a2.z); w[3] = f2bf(a2.w);
                w[4] = f2bf(a3.x); w[5] = f2bf(a3.y); w[6] = f2bf(a3.z); w[7] = f2bf(a3.w);
                *(u16x8*)&Ald[(kq * 2 + 1) * 1024 + arow * 8] = w;
                w[0] = f2bf(b0.x); w[1] = f2bf(b0.y); w[2] = f2bf(b0.z); w[3] = f2bf(b0.w);
                w[4] = f2bf(b1.x); w[5] = f2bf(b1.y); w[6] = f2bf(b1.z); w[7] = f2bf(b1.w);
                *(u16x8*)&Bld[(kq * 2) * 1024 + arow * 8] = w;
                w[0] = f2bf(b2.x); w[1] = f2bf(b2.y); w[2] = f2bf(b2.z); w[3] = f2bf(b2.w);
                w[4] = f2bf(b3.x); w[5] = f2bf(b3.y); w[6] = f2bf(b3.z); w[7] = f2bf(b3.w);
                *(u16x8*)&Bld[(kq * 2 + 1) * 1024 + arow * 8] = w;
            }
            __syncthreads();
            #pragma unroll
            for (int kh = 0; kh < 2; ++kh) {
                int kg = kh * 4 + (lane >> 4);
                short8 af[2], bfr[4];
                #pragma unroll
                for (int rf = 0; rf < 2; ++rf) {
                    int row = 32 * wr + rf * 16 + (lane & 15);
                    af[rf] = *(const short8*)&Ald[kg * 1024 + row * 8];
                }
                #pragma unroll
                for (int cf = 0; cf < 4; ++cf) {
                    int col = 64 * wc + cf * 16 + (lane & 15);
                    bfr[cf] = *(const short8*)&Bld[kg * 1024 + col * 8];
                }
                #pragma unroll
                for (int rf = 0; rf < 2; ++rf)
                    #pragma unroll
                    for (int cf = 0; cf < 4; ++cf)
                        acc[rf][cf] = __builtin_amdgcn_mfma_f32_16x16x32_bf16(
                            af[rf], bfr[cf], acc[rf][cf], 0, 0, 0);
            }
        }

        // epilogue: dist + top-2 update
        #pragma unroll
        for (int cf = 0; cf < 4; ++cf) {
            int col = colbase + 64 * wc + cf * 16 + (lane & 15);
            float sb = s_l[col], tb = t_l[col];
            #pragma unroll
            for (int rf = 0; rf < 2; ++rf)
                #pragma unroll
                for (int r = 0; r < 4; ++r) {
                    int i = rf * 4 + r;
                    float dot = acc[rf][cf][r];
                    float inner = sa[i] * sb * dot - ta[i] * tb;
                    float cd = fmaxf(-curv * inner, 1.0f + EPSF);
                    float d = __logf(cd + sqrtf(cd * cd - 1.0f)) * rsc;
                    if (col == tg[i]) d = 1e30f;   // mask positive
                    if (d < m1[i]) { m2[i] = m1[i]; m1[i] = d; }
                    else m2[i] = fminf(m2[i], d);
                }
        }
    }

    // reduce top-2 across the 16 lanes sharing each row
    #pragma unroll
    for (int mask = 1; mask <= 8; mask <<= 1) {
        #pragma unroll
        for (int i = 0; i < 8; ++i) {
            float o1 = __shfl_xor(m1[i], mask);
            float o2 = __shfl_xor(m2[i], mask);
            float n1 = fminf(m1[i], o1);
            float n2 = fminf(fmaxf(m1[i], o1), fminf(m2[i], o2));
            m1[i] = n1; m2[i] = n2;
        }
    }
    __syncthreads();
    if ((lane & 15) == 0) {
        #pragma unroll
        for (int i = 0; i < 8; ++i) {
            int rf = i >> 2, r = i & 3;
            int rl = 32 * wr + rf * 16 + rgrp * 4 + r;
            red[rl][wc][0] = m1[i];
            red[rl][wc][1] = m2[i];
        }
    }
    __syncthreads();
    if (tid < 128) {
        float a1 = red[tid][0][0], a2 = red[tid][0][1];
        float b1 = red[tid][1][0], b2 = red[tid][1][1];
        float p1 = fminf(a1, b1);
        float p2 = fminf(fmaxf(a1, b1), fminf(a2, b2));
        int row = rowbase + tid;
        part[(size_t)row * (SPLITC * 2) + split * 2 + 0] = p1;
        part[(size_t)row * (SPLITC * 2) + split * 2 + 1] = p2;
    }
}

// ---------------- final: merge splits + logsumexp loss ----------------
__global__ void final_kernel(const float* __restrict__ ws, float* __restrict__ out) {
    int row = blockIdx.x * 256 + threadIdx.x;
    if (row >= MM) return;
    const float* part = ws + PART_OFF;
    float p1 = 1e30f, p2 = 1e30f;
    #pragma unroll
    for (int s = 0; s < SPLITC; ++s) {
        float a1 = part[(size_t)row * 8 + s * 2];
        float a2 = part[(size_t)row * 8 + s * 2 + 1];
        float n1 = fminf(p1, a1);
        float n2 = fminf(fmaxf(p1, a1), fminf(p2, a2));
        p1 = n1; p2 = n2;
    }
    float dp = ws[POS_OFF + row];
    float denom = __expf(-dp) + __expf(-p1) + __expf(-p2);
    out[row] = __logf(denom) + dp;
}

extern "C" void kernel_launch(void* const* d_in, const int* in_sizes, int n_in,
                              void* d_out, int out_size, void* d_ws, size_t ws_size,
                              hipStream_t stream) {
    const float* X = (const float*)d_in[0];
    const float* Y = (const float*)d_in[1];
    const int* tgt = (const int*)d_in[2];
    const float* curv_log = (const float*)d_in[3];
    const float* ta_log = (const float*)d_in[4];
    const float* la_log = (const float*)d_in[5];
    float* ws = (float*)d_ws;
    float* out = (float*)d_out;

    prep_kernel<<<(MM + CC) / 4, 256, 0, stream>>>(X, Y, curv_log, ta_log, la_log, ws);
    pos_kernel<<<MM / 4, 256, 0, stream>>>(X, Y, tgt, curv_log, ws);
    main_kernel<<<(MM / BM) * SPLITC, TPB, 0, stream>>>(X, Y, tgt, curv_log, ws);
    final_kernel<<<MM / 256, 256, 0, stream>>>(ws, out);
}

// Round 2
// 156.498 us; speedup vs baseline: 1.4922x; 1.4922x over previous
//
#include <hip/hip_runtime.h>
#include <hip/hip_bf16.h>
#include <math.h>

#define MM 8192
#define CC 4096
#define DD 768
#define EPSF 1e-8f

#define BM 128
#define BN 128
#define BK 64
#define TPB 512
#define NCOLT (CC / BN)   // 32
#define NROWT (MM / BM)   // 64

// ---- ws layout ----
// bytes [0, XB_END): Xb bf16  (MM*DD)
// bytes [YB_OFF, ..): Yb bf16 (CC*DD)
// floats after FW_OFF: s_t, t_t, s_l, t_l, pos, part
#define XB_OFF 0
#define YB_OFF (MM * DD * 2)
#define FW_OFF (YB_OFF + CC * DD * 2)
#define S_T 0
#define T_T (MM)
#define S_L (2 * MM)
#define T_L (2 * MM + CC)
#define POS (2 * MM + 2 * CC)
#define PART (POS + MM)            // MM * NCOLT * 2 floats

typedef __attribute__((ext_vector_type(8))) short short8;
typedef __attribute__((ext_vector_type(4))) unsigned short u16x4;
typedef __attribute__((ext_vector_type(4))) float f32x4;

__device__ inline unsigned short f2bf(float f) {
    unsigned int u = __float_as_uint(f);
    u += 0x7FFF + ((u >> 16) & 1);   // RNE
    return (unsigned short)(u >> 16);
}

__device__ inline void gll16(const void* g, void* l) {
    __builtin_amdgcn_global_load_lds(
        (const __attribute__((address_space(1))) void*)(uintptr_t)g,
        (__attribute__((address_space(3))) void*)(unsigned)(uintptr_t)l,
        16, 0, 0);
}

// ---------------- prep+convert: per-row s,t + bf16 copies ----------------
__global__ void prep_conv_kernel(const float* __restrict__ X, const float* __restrict__ Y,
                                 const float* curv_log, const float* ta_log, const float* la_log,
                                 char* __restrict__ wsb) {
    unsigned short* Xb = (unsigned short*)(wsb + XB_OFF);
    unsigned short* Yb = (unsigned short*)(wsb + YB_OFF);
    float* fws = (float*)(wsb + FW_OFF);
    int wid = threadIdx.x >> 6, lane = threadIdx.x & 63;
    int row = blockIdx.x * 4 + wid;
    float curv = __expf(curv_log[0]);
    const float* src; unsigned short* dst; float alpha; float *s_out, *t_out; int idx;
    if (row < MM) {
        src = X + (size_t)row * DD; dst = Xb + (size_t)row * DD;
        alpha = __expf(ta_log[0]); s_out = fws + S_T; t_out = fws + T_T; idx = row;
    } else {
        int r = row - MM;
        src = Y + (size_t)r * DD; dst = Yb + (size_t)r * DD;
        alpha = __expf(la_log[0]); s_out = fws + S_L; t_out = fws + T_L; idx = r;
    }
    float n2 = 0.f;
    #pragma unroll
    for (int j = 0; j < 3; ++j) {
        float4 v = *(const float4*)(src + lane * 4 + 256 * j);
        n2 += v.x * v.x + v.y * v.y + v.z * v.z + v.w * v.w;
        u16x4 o; o[0] = f2bf(v.x); o[1] = f2bf(v.y); o[2] = f2bf(v.z); o[3] = f2bf(v.w);
        *(u16x4*)(dst + lane * 4 + 256 * j) = o;
    }
    #pragma unroll
    for (int m = 32; m; m >>= 1) n2 += __shfl_xor(n2, m);
    if (lane == 0) {
        float r = sqrtf(curv) * alpha * sqrtf(n2);
        float s = alpha * sinhf(r) / fmaxf(r, EPSF);
        float tt = sqrtf(1.0f / curv + s * s * n2);
        s_out[idx] = s;
        t_out[idx] = tt;
    }
}

// ---------------- pos: exact fp32 positive distance ----------------
__global__ void pos_kernel(const float* __restrict__ X, const float* __restrict__ Y,
                           const int* __restrict__ tgt, const float* curv_log,
                           char* __restrict__ wsb) {
    float* fws = (float*)(wsb + FW_OFF);
    int wid = threadIdx.x >> 6, lane = threadIdx.x & 63;
    int row = blockIdx.x * 4 + wid;
    if (row >= MM) return;
    float curv = __expf(curv_log[0]);
    int t = tgt[row];
    const float* xr = X + (size_t)row * DD;
    const float* yr = Y + (size_t)t * DD;
    float dot = 0.f;
    #pragma unroll
    for (int k = 0; k < DD / 64; ++k) dot += xr[lane + 64 * k] * yr[lane + 64 * k];
    #pragma unroll
    for (int m = 32; m; m >>= 1) dot += __shfl_xor(dot, m);
    if (lane == 0) {
        float inner = fws[S_T + row] * fws[S_L + t] * dot - fws[T_T + row] * fws[T_L + t];
        float cd = fmaxf(-curv * inner, 1.0f + EPSF);
        float d = __logf(cd + sqrtf(cd * cd - 1.0f)) * rsqrtf(curv);
        fws[POS + row] = d;
    }
}

// ---------------- main: bf16 MFMA GEMM + arccosh + top-2 ----------------
__global__ __launch_bounds__(TPB) void main_kernel(
    const int* __restrict__ tgt, const float* __restrict__ curv_log,
    char* __restrict__ wsb)
{
    __shared__ unsigned short Ald[8 * 128 * 8];   // [kg][row][8] bf16, 16KB
    __shared__ unsigned short Bld[8 * 128 * 8];
    __shared__ float red[128][2][2];

    const unsigned short* Xb = (const unsigned short*)(wsb + XB_OFF);
    const unsigned short* Yb = (const unsigned short*)(wsb + YB_OFF);
    float* fws = (float*)(wsb + FW_OFF);

    int tid = threadIdx.x;
    int lane = tid & 63, wid = tid >> 6;
    int wr = wid >> 1, wc = wid & 1;

    // XCD-aware bijective swizzle: xcd = bid&7 gets rowpanels xcd*8..+7, all 32 coltiles,
    // coltile-major so a B-panel is reused across 8 A-panels resident in that XCD's L2.
    int bid = blockIdx.x;
    int pos = bid >> 3;
    int coltile = pos >> 3;                      // 0..31
    int rowpanel = (bid & 7) * 8 + (pos & 7);    // 0..63
    int rowbase = rowpanel * BM;
    int colbase = coltile * BN;

    float curv = __expf(curv_log[0]);
    float rsc = rsqrtf(curv);

    // staging addresses: chunk c -> (kg=c>>7, row=c&127); thread stages chunks {tid, tid+512} of A and B
    const unsigned short* xsrc0 = Xb + (size_t)(rowbase + (tid & 127)) * DD + ((tid >> 7) * 8);
    const unsigned short* ysrc0 = Yb + (size_t)(colbase + (tid & 127)) * DD + ((tid >> 7) * 8);
    unsigned short* adst0 = Ald + tid * 8;
    unsigned short* bdst0 = Bld + tid * 8;

    f32x4 acc[2][4];
    #pragma unroll
    for (int a = 0; a < 2; ++a)
        #pragma unroll
        for (int b = 0; b < 4; ++b)
            acc[a][b] = (f32x4){0.f, 0.f, 0.f, 0.f};

    for (int ks = 0; ks < DD / BK; ++ks) {
        int k0 = ks * BK;
        __syncthreads();                       // prev iter's frag reads done
        gll16(xsrc0 + k0, adst0);
        gll16(xsrc0 + k0 + 32, adst0 + 4096);  // chunk tid+512: kg += 4 -> +32 elems, lds +4096 ushorts
        gll16(ysrc0 + k0, bdst0);
        gll16(ysrc0 + k0 + 32, bdst0 + 4096);
        __syncthreads();                       // barrier drains vmcnt -> tile ready
        #pragma unroll
        for (int kh = 0; kh < 2; ++kh) {
            int kg = kh * 4 + (lane >> 4);
            short8 af[2], bfr[4];
            #pragma unroll
            for (int rf = 0; rf < 2; ++rf) {
                int row = 32 * wr + rf * 16 + (lane & 15);
                af[rf] = *(const short8*)&Ald[kg * 1024 + row * 8];
            }
            #pragma unroll
            for (int cf = 0; cf < 4; ++cf) {
                int col = 64 * wc + cf * 16 + (lane & 15);
                bfr[cf] = *(const short8*)&Bld[kg * 1024 + col * 8];
            }
            #pragma unroll
            for (int rf = 0; rf < 2; ++rf)
                #pragma unroll
                for (int cf = 0; cf < 4; ++cf)
                    acc[rf][cf] = __builtin_amdgcn_mfma_f32_16x16x32_bf16(
                        af[rf], bfr[cf], acc[rf][cf], 0, 0, 0);
        }
    }

    // epilogue: dist + top-2 (loads of s/t/tgt sunk here to cut main-loop registers)
    int rgrp = lane >> 4;
    float sa[8], ta[8];
    int tg[8];
    #pragma unroll
    for (int rf = 0; rf < 2; ++rf)
        #pragma unroll
        for (int r = 0; r < 4; ++r) {
            int row = rowbase + 32 * wr + rf * 16 + rgrp * 4 + r;
            sa[rf * 4 + r] = fws[S_T + row];
            ta[rf * 4 + r] = fws[T_T + row];
            tg[rf * 4 + r] = tgt[row];
        }

    float m1[8], m2[8];
    #pragma unroll
    for (int i = 0; i < 8; ++i) { m1[i] = 1e30f; m2[i] = 1e30f; }

    #pragma unroll
    for (int cf = 0; cf < 4; ++cf) {
        int col = colbase + 64 * wc + cf * 16 + (lane & 15);
        float sb = fws[S_L + col], tb = fws[T_L + col];
        #pragma unroll
        for (int rf = 0; rf < 2; ++rf)
            #pragma unroll
            for (int r = 0; r < 4; ++r) {
                int i = rf * 4 + r;
                float dot = acc[rf][cf][r];
                float inner = sa[i] * sb * dot - ta[i] * tb;
                float cd = fmaxf(-curv * inner, 1.0f + EPSF);
                float d = __logf(cd + sqrtf(cd * cd - 1.0f)) * rsc;
                if (col == tg[i]) d = 1e30f;
                if (d < m1[i]) { m2[i] = m1[i]; m1[i] = d; }
                else m2[i] = fminf(m2[i], d);
            }
    }

    #pragma unroll
    for (int mask = 1; mask <= 8; mask <<= 1) {
        #pragma unroll
        for (int i = 0; i < 8; ++i) {
            float o1 = __shfl_xor(m1[i], mask);
            float o2 = __shfl_xor(m2[i], mask);
            float n1 = fminf(m1[i], o1);
            float n2 = fminf(fmaxf(m1[i], o1), fminf(m2[i], o2));
            m1[i] = n1; m2[i] = n2;
        }
    }
    __syncthreads();
    if ((lane & 15) == 0) {
        #pragma unroll
        for (int i = 0; i < 8; ++i) {
            int rf = i >> 2, r = i & 3;
            int rl = 32 * wr + rf * 16 + rgrp * 4 + r;
            red[rl][wc][0] = m1[i];
            red[rl][wc][1] = m2[i];
        }
    }
    __syncthreads();
    if (tid < 128) {
        float a1 = red[tid][0][0], a2 = red[tid][0][1];
        float b1 = red[tid][1][0], b2 = red[tid][1][1];
        float p1 = fminf(a1, b1);
        float p2 = fminf(fmaxf(a1, b1), fminf(a2, b2));
        int row = rowbase + tid;
        fws[PART + (size_t)row * (NCOLT * 2) + coltile * 2 + 0] = p1;
        fws[PART + (size_t)row * (NCOLT * 2) + coltile * 2 + 1] = p2;
    }
}

// ---------------- final: merge partials + loss ----------------
__global__ void final_kernel(const char* __restrict__ wsb, float* __restrict__ out) {
    const float* fws = (const float*)(wsb + FW_OFF);
    int row = blockIdx.x * 256 + threadIdx.x;
    if (row >= MM) return;
    const float* p = fws + PART + (size_t)row * (NCOLT * 2);
    float p1 = 1e30f, p2 = 1e30f;
    #pragma unroll
    for (int s = 0; s < NCOLT; ++s) {
        float a1 = p[s * 2], a2 = p[s * 2 + 1];
        float n1 = fminf(p1, a1);
        float n2 = fminf(fmaxf(p1, a1), fminf(p2, a2));
        p1 = n1; p2 = n2;
    }
    float dp = fws[POS + row];
    float denom = __expf(-dp) + __expf(-p1) + __expf(-p2);
    out[row] = __logf(denom) + dp;
}

extern "C" void kernel_launch(void* const* d_in, const int* in_sizes, int n_in,
                              void* d_out, int out_size, void* d_ws, size_t ws_size,
                              hipStream_t stream) {
    const float* X = (const float*)d_in[0];
    const float* Y = (const float*)d_in[1];
    const int* tgt = (const int*)d_in[2];
    const float* curv_log = (const float*)d_in[3];
    const float* ta_log = (const float*)d_in[4];
    const float* la_log = (const float*)d_in[5];
    char* wsb = (char*)d_ws;
    float* out = (float*)d_out;

    prep_conv_kernel<<<(MM + CC) / 4, 256, 0, stream>>>(X, Y, curv_log, ta_log, la_log, wsb);
    pos_kernel<<<MM / 4, 256, 0, stream>>>(X, Y, tgt, curv_log, wsb);
    main_kernel<<<NROWT * NCOLT, TPB, 0, stream>>>(tgt, curv_log, wsb);
    final_kernel<<<MM / 256, 256, 0, stream>>>(wsb, out);
}

// Round 3
// 133.084 us; speedup vs baseline: 1.7547x; 1.1759x over previous
//
#include <hip/hip_runtime.h>
#include <hip/hip_bf16.h>
#include <math.h>

#define MM 8192
#define CC 4096
#define DD 768
#define EPSF 1e-8f

#define BM 128
#define BN 128
#define BK 64
#define TPB 512
#define NCOLT (CC / BN)   // 32
#define NROWT (MM / BM)   // 64
#define NKS (DD / BK)     // 12

// ---- ws layout ----
#define XB_OFF 0
#define YB_OFF (MM * DD * 2)
#define FW_OFF (YB_OFF + CC * DD * 2)
#define S_T 0
#define T_T (MM)
#define S_L (2 * MM)
#define T_L (2 * MM + CC)
#define POS (2 * MM + 2 * CC)
#define PART (POS + MM)            // MM * NCOLT * 2 floats (top-2 largest inner)

typedef __attribute__((ext_vector_type(8))) short short8;
typedef __attribute__((ext_vector_type(4))) unsigned short u16x4;
typedef __attribute__((ext_vector_type(4))) float f32x4;

__device__ inline unsigned short f2bf(float f) {
    unsigned int u = __float_as_uint(f);
    u += 0x7FFF + ((u >> 16) & 1);   // RNE
    return (unsigned short)(u >> 16);
}

__device__ inline void gll16(const void* g, void* l) {
    __builtin_amdgcn_global_load_lds(
        (const __attribute__((address_space(1))) void*)(uintptr_t)g,
        (__attribute__((address_space(3))) void*)(unsigned)(uintptr_t)l,
        16, 0, 0);
}

// ---------------- prep+convert: per-row s,t + bf16 copies ----------------
__global__ void prep_conv_kernel(const float* __restrict__ X, const float* __restrict__ Y,
                                 const float* curv_log, const float* ta_log, const float* la_log,
                                 char* __restrict__ wsb) {
    unsigned short* Xb = (unsigned short*)(wsb + XB_OFF);
    unsigned short* Yb = (unsigned short*)(wsb + YB_OFF);
    float* fws = (float*)(wsb + FW_OFF);
    int wid = threadIdx.x >> 6, lane = threadIdx.x & 63;
    int row = blockIdx.x * 4 + wid;
    float curv = __expf(curv_log[0]);
    const float* src; unsigned short* dst; float alpha; float *s_out, *t_out; int idx;
    if (row < MM) {
        src = X + (size_t)row * DD; dst = Xb + (size_t)row * DD;
        alpha = __expf(ta_log[0]); s_out = fws + S_T; t_out = fws + T_T; idx = row;
    } else {
        int r = row - MM;
        src = Y + (size_t)r * DD; dst = Yb + (size_t)r * DD;
        alpha = __expf(la_log[0]); s_out = fws + S_L; t_out = fws + T_L; idx = r;
    }
    float n2 = 0.f;
    #pragma unroll
    for (int j = 0; j < 3; ++j) {
        float4 v = *(const float4*)(src + lane * 4 + 256 * j);
        n2 += v.x * v.x + v.y * v.y + v.z * v.z + v.w * v.w;
        u16x4 o; o[0] = f2bf(v.x); o[1] = f2bf(v.y); o[2] = f2bf(v.z); o[3] = f2bf(v.w);
        *(u16x4*)(dst + lane * 4 + 256 * j) = o;
    }
    #pragma unroll
    for (int m = 32; m; m >>= 1) n2 += __shfl_xor(n2, m);
    if (lane == 0) {
        float r = sqrtf(curv) * alpha * sqrtf(n2);
        float s = alpha * sinhf(r) / fmaxf(r, EPSF);
        float tt = sqrtf(1.0f / curv + s * s * n2);
        s_out[idx] = s;
        t_out[idx] = tt;
    }
}

// ---------------- pos: exact fp32 positive distance ----------------
__global__ void pos_kernel(const float* __restrict__ X, const float* __restrict__ Y,
                           const int* __restrict__ tgt, const float* curv_log,
                           char* __restrict__ wsb) {
    float* fws = (float*)(wsb + FW_OFF);
    int wid = threadIdx.x >> 6, lane = threadIdx.x & 63;
    int row = blockIdx.x * 4 + wid;
    if (row >= MM) return;
    float curv = __expf(curv_log[0]);
    int t = tgt[row];
    const float* xr = X + (size_t)row * DD;
    const float* yr = Y + (size_t)t * DD;
    float dot = 0.f;
    #pragma unroll
    for (int k = 0; k < DD / 64; ++k) dot += xr[lane + 64 * k] * yr[lane + 64 * k];
    #pragma unroll
    for (int m = 32; m; m >>= 1) dot += __shfl_xor(dot, m);
    if (lane == 0) {
        float inner = fws[S_T + row] * fws[S_L + t] * dot - fws[T_T + row] * fws[T_L + t];
        float cd = fmaxf(-curv * inner, 1.0f + EPSF);
        float d = __logf(cd + sqrtf(cd * cd - 1.0f)) * rsqrtf(curv);
        fws[POS + row] = d;
    }
}

// ---------------- main: double-buffered bf16 MFMA GEMM + top-2 largest inner ----------------
__global__ __launch_bounds__(TPB) void main_kernel(
    const int* __restrict__ tgt, const float* __restrict__ curv_log,
    char* __restrict__ wsb)
{
    __shared__ unsigned short Ald[2 * 8192];   // [buf][kg][row][8] bf16, 2x16KB
    __shared__ unsigned short Bld[2 * 8192];
    __shared__ float red[128][2][2];

    const unsigned short* Xb = (const unsigned short*)(wsb + XB_OFF);
    const unsigned short* Yb = (const unsigned short*)(wsb + YB_OFF);
    float* fws = (float*)(wsb + FW_OFF);

    int tid = threadIdx.x;
    int lane = tid & 63, wid = tid >> 6;
    int wr = wid >> 1, wc = wid & 1;

    // XCD-aware bijective swizzle (2048 blocks % 8 == 0)
    int bid = blockIdx.x;
    int pos = bid >> 3;
    int coltile = pos >> 3;                      // 0..31
    int rowpanel = (bid & 7) * 8 + (pos & 7);    // 0..63
    int rowbase = rowpanel * BM;
    int colbase = coltile * BN;

    float curv = __expf(curv_log[0]);

    // staging: chunk c -> (kg=c>>7, row=c&127); thread stages chunks {tid, tid+512}
    const unsigned short* xs = Xb + (size_t)(rowbase + (tid & 127)) * DD + ((tid >> 7) * 8);
    const unsigned short* ys = Yb + (size_t)(colbase + (tid & 127)) * DD + ((tid >> 7) * 8);
    unsigned short* ad = Ald + tid * 8;
    unsigned short* bd = Bld + tid * 8;

    f32x4 acc[2][4];
    #pragma unroll
    for (int a = 0; a < 2; ++a)
        #pragma unroll
        for (int b = 0; b < 4; ++b)
            acc[a][b] = (f32x4){0.f, 0.f, 0.f, 0.f};

    // prologue: stage ks=0 into buf 0
    gll16(xs, ad);      gll16(xs + 32, ad + 4096);
    gll16(ys, bd);      gll16(ys + 32, bd + 4096);
    __syncthreads();

    int buf = 0;
    for (int ks = 0; ks < NKS; ++ks) {
        if (ks < NKS - 1) {                      // stage next tile into other buffer
            int k0 = (ks + 1) * BK;
            unsigned short* a2 = ad + (buf ^ 1) * 8192;
            unsigned short* b2 = bd + (buf ^ 1) * 8192;
            gll16(xs + k0, a2);      gll16(xs + k0 + 32, a2 + 4096);
            gll16(ys + k0, b2);      gll16(ys + k0 + 32, b2 + 4096);
        }
        const unsigned short* Ab = Ald + buf * 8192;
        const unsigned short* Bb = Bld + buf * 8192;
        #pragma unroll
        for (int kh = 0; kh < 2; ++kh) {
            int kg = kh * 4 + (lane >> 4);
            short8 af[2], bfr[4];
            #pragma unroll
            for (int rf = 0; rf < 2; ++rf) {
                int row = 32 * wr + rf * 16 + (lane & 15);
                af[rf] = *(const short8*)&Ab[kg * 1024 + row * 8];
            }
            #pragma unroll
            for (int cf = 0; cf < 4; ++cf) {
                int col = 64 * wc + cf * 16 + (lane & 15);
                bfr[cf] = *(const short8*)&Bb[kg * 1024 + col * 8];
            }
            #pragma unroll
            for (int rf = 0; rf < 2; ++rf)
                #pragma unroll
                for (int cf = 0; cf < 4; ++cf)
                    acc[rf][cf] = __builtin_amdgcn_mfma_f32_16x16x32_bf16(
                        af[rf], bfr[cf], acc[rf][cf], 0, 0, 0);
        }
        __syncthreads();                         // vmcnt(0)+lgkm(0)+barrier: next buf ready
        buf ^= 1;
    }

    // ---- epilogue: top-2 LARGEST Lorentz inner (monotone with smallest distance) ----
    int rgrp = lane >> 4;
    float sa[8], ta[8];
    int tg[8];
    #pragma unroll
    for (int rf = 0; rf < 2; ++rf)
        #pragma unroll
        for (int r = 0; r < 4; ++r) {
            int row = rowbase + 32 * wr + rf * 16 + rgrp * 4 + r;
            sa[rf * 4 + r] = fws[S_T + row];
            ta[rf * 4 + r] = fws[T_T + row];
            tg[rf * 4 + r] = tgt[row];
        }

    float m1[8], m2[8];
    #pragma unroll
    for (int i = 0; i < 8; ++i) { m1[i] = -1e30f; m2[i] = -1e30f; }

    #pragma unroll
    for (int cf = 0; cf < 4; ++cf) {
        int col = colbase + 64 * wc + cf * 16 + (lane & 15);
        float sb = fws[S_L + col], tb = fws[T_L + col];
        #pragma unroll
        for (int rf = 0; rf < 2; ++rf)
            #pragma unroll
            for (int r = 0; r < 4; ++r) {
                int i = rf * 4 + r;
                float v = sa[i] * (sb * acc[rf][cf][r]) - ta[i] * tb;  // Lorentz inner
                if (col == tg[i]) v = -3e38f;                          // mask positive
                float n1 = fmaxf(m1[i], v);
                m2[i] = fmaxf(m2[i], fminf(m1[i], v));
                m1[i] = n1;
            }
    }

    #pragma unroll
    for (int mask = 1; mask <= 8; mask <<= 1) {
        #pragma unroll
        for (int i = 0; i < 8; ++i) {
            float o1 = __shfl_xor(m1[i], mask);
            float o2 = __shfl_xor(m2[i], mask);
            float n1 = fmaxf(m1[i], o1);
            float n2 = fmaxf(fminf(m1[i], o1), fmaxf(m2[i], o2));
            m1[i] = n1; m2[i] = n2;
        }
    }
    __syncthreads();
    if ((lane & 15) == 0) {
        #pragma unroll
        for (int i = 0; i < 8; ++i) {
            int rf = i >> 2, r = i & 3;
            int rl = 32 * wr + rf * 16 + rgrp * 4 + r;
            red[rl][wc][0] = m1[i];
            red[rl][wc][1] = m2[i];
        }
    }
    __syncthreads();
    if (tid < 128) {
        float a1 = red[tid][0][0], a2 = red[tid][0][1];
        float b1 = red[tid][1][0], b2 = red[tid][1][1];
        float p1 = fmaxf(a1, b1);
        float p2 = fmaxf(fminf(a1, b1), fmaxf(a2, b2));
        int row = rowbase + tid;
        fws[PART + (size_t)row * (NCOLT * 2) + coltile * 2 + 0] = p1;
        fws[PART + (size_t)row * (NCOLT * 2) + coltile * 2 + 1] = p2;
    }
}

// ---------------- final: merge partials, arccosh on 2 winners, loss ----------------
__global__ void final_kernel(const char* __restrict__ wsb, const float* __restrict__ curv_log,
                             float* __restrict__ out) {
    const float* fws = (const float*)(wsb + FW_OFF);
    int row = blockIdx.x * 256 + threadIdx.x;
    if (row >= MM) return;
    float curv = __expf(curv_log[0]);
    float rsc = rsqrtf(curv);
    const float* p = fws + PART + (size_t)row * (NCOLT * 2);
    float p1 = -1e30f, p2 = -1e30f;
    #pragma unroll
    for (int s = 0; s < NCOLT; ++s) {
        float a1 = p[s * 2], a2 = p[s * 2 + 1];
        float n1 = fmaxf(p1, a1);
        float n2 = fmaxf(fminf(p1, a1), fmaxf(p2, a2));
        p1 = n1; p2 = n2;
    }
    float cd1 = fmaxf(-curv * p1, 1.0f + EPSF);
    float d1 = __logf(cd1 + sqrtf(cd1 * cd1 - 1.0f)) * rsc;
    float cd2 = fmaxf(-curv * p2, 1.0f + EPSF);
    float d2 = __logf(cd2 + sqrtf(cd2 * cd2 - 1.0f)) * rsc;
    float dp = fws[POS + row];
    float denom = __expf(-dp) + __expf(-d1) + __expf(-d2);
    out[row] = __logf(denom) + dp;
}

extern "C" void kernel_launch(void* const* d_in, const int* in_sizes, int n_in,
                              void* d_out, int out_size, void* d_ws, size_t ws_size,
                              hipStream_t stream) {
    const float* X = (const float*)d_in[0];
    const float* Y = (const float*)d_in[1];
    const int* tgt = (const int*)d_in[2];
    const float* curv_log = (const float*)d_in[3];
    const float* ta_log = (const float*)d_in[4];
    const float* la_log = (const float*)d_in[5];
    char* wsb = (char*)d_ws;
    float* out = (float*)d_out;

    prep_conv_kernel<<<(MM + CC) / 4, 256, 0, stream>>>(X, Y, curv_log, ta_log, la_log, wsb);
    pos_kernel<<<MM / 4, 256, 0, stream>>>(X, Y, tgt, curv_log, wsb);
    main_kernel<<<NROWT * NCOLT, TPB, 0, stream>>>(tgt, curv_log, wsb);
    final_kernel<<<MM / 256, 256, 0, stream>>>(wsb, curv_log, out);
}

// Round 4
// 127.183 us; speedup vs baseline: 1.8361x; 1.0464x over previous
//
#include <hip/hip_runtime.h>
#include <hip/hip_bf16.h>
#include <math.h>

#define MM 8192
#define CC 4096
#define DD 768
#define EPSF 1e-8f

#define BM 256
#define BN 256
#define BK 64
#define TPB 512
#define NKT (DD / BK)          // 12 K-tiles
#define NROWT (MM / BM)        // 32
#define NCOLT (CC / BN)        // 16

// ---- ws layout ----
#define XB_OFF 0
#define YB_OFF (MM * DD * 2)
#define FW_OFF (YB_OFF + CC * DD * 2)
#define S_T 0
#define T_T (MM)
#define S_L (2 * MM)
#define T_L (2 * MM + CC)
#define CA_T (2 * MM + 2 * CC)         // t_t / s_t per text row
#define POS  (CA_T + MM)
#define PART (POS + MM)                // MM * NCOLT * 2 floats (top-2 largest u)

typedef __attribute__((ext_vector_type(8))) short short8;
typedef __attribute__((ext_vector_type(4))) unsigned short u16x4;
typedef __attribute__((ext_vector_type(4))) float f32x4;

__device__ inline unsigned short f2bf(float f) {
    unsigned int u = __float_as_uint(f);
    u += 0x7FFF + ((u >> 16) & 1);   // RNE
    return (unsigned short)(u >> 16);
}

__device__ inline void gll16(const void* g, void* l) {
    __builtin_amdgcn_global_load_lds(
        (const __attribute__((address_space(1))) void*)(uintptr_t)g,
        (__attribute__((address_space(3))) void*)(unsigned)(uintptr_t)l,
        16, 0, 0);
}

#define BAR() do { __builtin_amdgcn_sched_barrier(0); __builtin_amdgcn_s_barrier(); __builtin_amdgcn_sched_barrier(0); } while (0)

// ---------------- prep+convert: per-row s,t,ca + bf16 copies ----------------
__global__ void prep_conv_kernel(const float* __restrict__ X, const float* __restrict__ Y,
                                 const float* curv_log, const float* ta_log, const float* la_log,
                                 char* __restrict__ wsb) {
    unsigned short* Xb = (unsigned short*)(wsb + XB_OFF);
    unsigned short* Yb = (unsigned short*)(wsb + YB_OFF);
    float* fws = (float*)(wsb + FW_OFF);
    int wid = threadIdx.x >> 6, lane = threadIdx.x & 63;
    int row = blockIdx.x * 4 + wid;
    float curv = __expf(curv_log[0]);
    const float* src; unsigned short* dst; float alpha; int idx; int is_text;
    if (row < MM) {
        src = X + (size_t)row * DD; dst = Xb + (size_t)row * DD;
        alpha = __expf(ta_log[0]); idx = row; is_text = 1;
    } else {
        int r = row - MM;
        src = Y + (size_t)r * DD; dst = Yb + (size_t)r * DD;
        alpha = __expf(la_log[0]); idx = r; is_text = 0;
    }
    float n2 = 0.f;
    #pragma unroll
    for (int j = 0; j < 3; ++j) {
        float4 v = *(const float4*)(src + lane * 4 + 256 * j);
        n2 += v.x * v.x + v.y * v.y + v.z * v.z + v.w * v.w;
        u16x4 o; o[0] = f2bf(v.x); o[1] = f2bf(v.y); o[2] = f2bf(v.z); o[3] = f2bf(v.w);
        *(u16x4*)(dst + lane * 4 + 256 * j) = o;
    }
    #pragma unroll
    for (int m = 32; m; m >>= 1) n2 += __shfl_xor(n2, m);
    if (lane == 0) {
        float r = sqrtf(curv) * alpha * sqrtf(n2);
        float s = alpha * sinhf(r) / fmaxf(r, EPSF);
        float tt = sqrtf(1.0f / curv + s * s * n2);
        if (is_text) {
            fws[S_T + idx] = s; fws[T_T + idx] = tt; fws[CA_T + idx] = tt / s;
        } else {
            fws[S_L + idx] = s; fws[T_L + idx] = tt;
        }
    }
}

// ---------------- pos: exact fp32 positive distance ----------------
__global__ void pos_kernel(const float* __restrict__ X, const float* __restrict__ Y,
                           const int* __restrict__ tgt, const float* curv_log,
                           char* __restrict__ wsb) {
    float* fws = (float*)(wsb + FW_OFF);
    int wid = threadIdx.x >> 6, lane = threadIdx.x & 63;
    int row = blockIdx.x * 4 + wid;
    if (row >= MM) return;
    float curv = __expf(curv_log[0]);
    int t = tgt[row];
    const float* xr = X + (size_t)row * DD;
    const float* yr = Y + (size_t)t * DD;
    float dot = 0.f;
    #pragma unroll
    for (int k = 0; k < DD / 64; ++k) dot += xr[lane + 64 * k] * yr[lane + 64 * k];
    #pragma unroll
    for (int m = 32; m; m >>= 1) dot += __shfl_xor(dot, m);
    if (lane == 0) {
        float inner = fws[S_T + row] * fws[S_L + t] * dot - fws[T_T + row] * fws[T_L + t];
        float cd = fmaxf(-curv * inner, 1.0f + EPSF);
        float d = __logf(cd + sqrtf(cd * cd - 1.0f)) * rsqrtf(curv);
        fws[POS + row] = d;
    }
}

// ---------------- main: 256x256 8-phase bf16 MFMA GEMM + top-2 largest u ----------------
__global__ __launch_bounds__(TPB, 2) void main_kernel(
    const int* __restrict__ tgt, char* __restrict__ wsb)
{
    // region r = (kt&1)*2 + khalf; each region = [kg 0..3][row 0..255][8 elems] = 8192 ushorts (16KB)
    __shared__ unsigned short Ald[4 * 8192];   // 64KB
    __shared__ unsigned short Bld[4 * 8192];   // 64KB
    __shared__ float red[256][4][2];           // 8KB

    const unsigned short* Xb = (const unsigned short*)(wsb + XB_OFF);
    const unsigned short* Yb = (const unsigned short*)(wsb + YB_OFF);
    float* fws = (float*)(wsb + FW_OFF);

    int tid = threadIdx.x;
    int lane = tid & 63, wid = tid >> 6;
    int wr = wid >> 2, wc = wid & 3;           // 2 row-groups x 4 col-groups
    int l15 = lane & 15, rgrp = lane >> 4;

    // XCD-bijective swizzle: 512 blocks, xcd = bid&7 owns 4 rowpanels x all 16 coltiles
    int bid = blockIdx.x;
    int pos = bid >> 3;
    int coltile = pos >> 2;                    // 0..15
    int rowpanel = (bid & 7) * 4 + (pos & 3);  // 0..31
    int rowbase = rowpanel * BM;
    int colbase = coltile * BN;

    // staging: thread t covers chunks t and t+512 of each 16KB half-tile
    const unsigned short* xsb = Xb + (size_t)(rowbase + (tid & 255)) * DD + ((tid >> 8) * 8);
    const unsigned short* ysb = Yb + (size_t)(colbase + (tid & 255)) * DD + ((tid >> 8) * 8);
    unsigned short* adst = Ald + tid * 8;
    unsigned short* bdst = Bld + tid * 8;

#define STAGE_A(kt_, kh_) do { int rg_ = (((kt_) & 1) * 2 + (kh_)); \
    gll16(xsb + (kt_) * 64 + (kh_) * 32, adst + rg_ * 8192); \
    gll16(xsb + (kt_) * 64 + (kh_) * 32 + 16, adst + rg_ * 8192 + 4096); } while (0)
#define STAGE_B(kt_, kh_) do { int rg_ = (((kt_) & 1) * 2 + (kh_)); \
    gll16(ysb + (kt_) * 64 + (kh_) * 32, bdst + rg_ * 8192); \
    gll16(ysb + (kt_) * 64 + (kh_) * 32 + 16, bdst + rg_ * 8192 + 4096); } while (0)

    // fragment read bases
    const unsigned short* aread = Ald + rgrp * 2048 + (wr * 128 + l15) * 8;
    const unsigned short* bread = Bld + rgrp * 2048 + (wc * 64 + l15) * 8;

    f32x4 acc[8][4];
    #pragma unroll
    for (int a = 0; a < 8; ++a)
        #pragma unroll
        for (int b = 0; b < 4; ++b)
            acc[a][b] = (f32x4){0.f, 0.f, 0.f, 0.f};

    // prologue: stage 6 half-tiles in consumption order, wait first 4 (8 loads)
    STAGE_A(0, 0); STAGE_B(0, 0); STAGE_A(0, 1); STAGE_B(0, 1); STAGE_A(1, 0); STAGE_B(1, 0);
    asm volatile("s_waitcnt vmcnt(4)" ::: "memory");
    BAR();

    #pragma unroll
    for (int kt = 0; kt < NKT; ++kt) {
        const int rg0 = (kt & 1) * 2;      // khalf 0 region
        const int rg1 = rg0 + 1;           // khalf 1 region
        short8 af[4], bf[4];

        // ---- q0: kh0, M-half 0 ----
        if (kt == NKT - 1) { asm volatile("s_waitcnt vmcnt(0)" ::: "memory"); }
        else               { asm volatile("s_waitcnt vmcnt(4)" ::: "memory"); }
        #pragma unroll
        for (int nf = 0; nf < 4; ++nf) bf[nf] = *(const short8*)(bread + rg0 * 8192 + nf * 128);
        #pragma unroll
        for (int mf = 0; mf < 4; ++mf) af[mf] = *(const short8*)(aread + rg0 * 8192 + mf * 128);
        if (kt < NKT - 1) STAGE_A(kt + 1, 1);
        BAR();
        __builtin_amdgcn_s_setprio(1);
        #pragma unroll
        for (int mf = 0; mf < 4; ++mf)
            #pragma unroll
            for (int nf = 0; nf < 4; ++nf)
                acc[mf][nf] = __builtin_amdgcn_mfma_f32_16x16x32_bf16(af[mf], bf[nf], acc[mf][nf], 0, 0, 0);
        __builtin_amdgcn_s_setprio(0);
        BAR();

        // ---- q1: kh0, M-half 1 ----
        #pragma unroll
        for (int mf = 0; mf < 4; ++mf) af[mf] = *(const short8*)(aread + rg0 * 8192 + 512 + mf * 128);
        if (kt < NKT - 1) STAGE_B(kt + 1, 1);
        BAR();
        __builtin_amdgcn_s_setprio(1);
        #pragma unroll
        for (int mf = 0; mf < 4; ++mf)
            #pragma unroll
            for (int nf = 0; nf < 4; ++nf)
                acc[4 + mf][nf] = __builtin_amdgcn_mfma_f32_16x16x32_bf16(af[mf], bf[nf], acc[4 + mf][nf], 0, 0, 0);
        __builtin_amdgcn_s_setprio(0);
        BAR();

        // ---- q2: kh1, M-half 0 ----
        #pragma unroll
        for (int nf = 0; nf < 4; ++nf) bf[nf] = *(const short8*)(bread + rg1 * 8192 + nf * 128);
        #pragma unroll
        for (int mf = 0; mf < 4; ++mf) af[mf] = *(const short8*)(aread + rg1 * 8192 + mf * 128);
        if (kt < NKT - 2) STAGE_A(kt + 2, 0);
        BAR();
        __builtin_amdgcn_s_setprio(1);
        #pragma unroll
        for (int mf = 0; mf < 4; ++mf)
            #pragma unroll
            for (int nf = 0; nf < 4; ++nf)
                acc[mf][nf] = __builtin_amdgcn_mfma_f32_16x16x32_bf16(af[mf], bf[nf], acc[mf][nf], 0, 0, 0);
        __builtin_amdgcn_s_setprio(0);
        BAR();

        // ---- q3: kh1, M-half 1 ----
        #pragma unroll
        for (int mf = 0; mf < 4; ++mf) af[mf] = *(const short8*)(aread + rg1 * 8192 + 512 + mf * 128);
        if (kt < NKT - 2) STAGE_B(kt + 2, 0);
        BAR();
        __builtin_amdgcn_s_setprio(1);
        #pragma unroll
        for (int mf = 0; mf < 4; ++mf)
            #pragma unroll
            for (int nf = 0; nf < 4; ++nf)
                acc[4 + mf][nf] = __builtin_amdgcn_mfma_f32_16x16x32_bf16(af[mf], bf[nf], acc[4 + mf][nf], 0, 0, 0);
        __builtin_amdgcn_s_setprio(0);
        BAR();
    }

    // ---- epilogue: per-row top-2 of u = sb*dot - ca*tb (argtop2 == top2 of inner; sa>0) ----
    int colb = colbase + wc * 64 + l15;
    float sbv[4], tbv[4];
    #pragma unroll
    for (int nf = 0; nf < 4; ++nf) { sbv[nf] = fws[S_L + colb + nf * 16]; tbv[nf] = fws[T_L + colb + nf * 16]; }

    float m1[32], m2[32];
    #pragma unroll
    for (int mf = 0; mf < 8; ++mf) {
        int rw = rowbase + wr * 128 + mf * 16 + rgrp * 4;
        #pragma unroll
        for (int j = 0; j < 4; ++j) {
            float ca = fws[CA_T + rw + j];
            int tgj = tgt[rw + j];
            float a = -3.4e38f, b = -3.4e38f;
            #pragma unroll
            for (int nf = 0; nf < 4; ++nf) {
                float u = sbv[nf] * acc[mf][nf][j] - ca * tbv[nf];
                if (colb + nf * 16 == tgj) u = -3.4e38f;
                float n1 = fmaxf(a, u);
                b = fmaxf(b, fminf(a, u));
                a = n1;
            }
            m1[mf * 4 + j] = a; m2[mf * 4 + j] = b;
        }
    }
    #pragma unroll
    for (int mask = 1; mask <= 8; mask <<= 1)
        #pragma unroll
        for (int i = 0; i < 32; ++i) {
            float o1 = __shfl_xor(m1[i], mask);
            float o2 = __shfl_xor(m2[i], mask);
            float n1 = fmaxf(m1[i], o1);
            m2[i] = fmaxf(fminf(m1[i], o1), fmaxf(m2[i], o2));
            m1[i] = n1;
        }
    if (l15 == 0) {
        #pragma unroll
        for (int mf = 0; mf < 8; ++mf)
            #pragma unroll
            for (int j = 0; j < 4; ++j) {
                int rl = wr * 128 + mf * 16 + rgrp * 4 + j;
                red[rl][wc][0] = m1[mf * 4 + j];
                red[rl][wc][1] = m2[mf * 4 + j];
            }
    }
    __syncthreads();
    if (tid < 256) {
        float p1 = -3.4e38f, p2 = -3.4e38f;
        #pragma unroll
        for (int g = 0; g < 4; ++g) {
            float a1 = red[tid][g][0], a2 = red[tid][g][1];
            float n1 = fmaxf(p1, a1);
            p2 = fmaxf(fminf(p1, a1), fmaxf(p2, a2));
            p1 = n1;
        }
        int row = rowbase + tid;
        fws[PART + ((size_t)row * NCOLT + coltile) * 2 + 0] = p1;
        fws[PART + ((size_t)row * NCOLT + coltile) * 2 + 1] = p2;
    }
}

// ---------------- final: merge partials, arccosh on winners, loss ----------------
__global__ void final_kernel(const char* __restrict__ wsb, const float* __restrict__ curv_log,
                             float* __restrict__ out) {
    const float* fws = (const float*)(wsb + FW_OFF);
    int row = blockIdx.x * 256 + threadIdx.x;
    if (row >= MM) return;
    float curv = __expf(curv_log[0]);
    float rsc = rsqrtf(curv);
    const float* p = fws + PART + (size_t)row * (NCOLT * 2);
    float p1 = -3.4e38f, p2 = -3.4e38f;
    #pragma unroll
    for (int s = 0; s < NCOLT; ++s) {
        float a1 = p[s * 2], a2 = p[s * 2 + 1];
        float n1 = fmaxf(p1, a1);
        p2 = fmaxf(fminf(p1, a1), fmaxf(p2, a2));
        p1 = n1;
    }
    float sa = fws[S_T + row];
    float i1 = sa * p1, i2 = sa * p2;          // back to Lorentz inner
    float cd1 = fmaxf(-curv * i1, 1.0f + EPSF);
    float d1 = __logf(cd1 + sqrtf(cd1 * cd1 - 1.0f)) * rsc;
    float cd2 = fmaxf(-curv * i2, 1.0f + EPSF);
    float d2 = __logf(cd2 + sqrtf(cd2 * cd2 - 1.0f)) * rsc;
    float dp = fws[POS + row];
    float denom = __expf(-dp) + __expf(-d1) + __expf(-d2);
    out[row] = __logf(denom) + dp;
}

extern "C" void kernel_launch(void* const* d_in, const int* in_sizes, int n_in,
                              void* d_out, int out_size, void* d_ws, size_t ws_size,
                              hipStream_t stream) {
    const float* X = (const float*)d_in[0];
    const float* Y = (const float*)d_in[1];
    const int* tgt = (const int*)d_in[2];
    const float* curv_log = (const float*)d_in[3];
    const float* ta_log = (const float*)d_in[4];
    const float* la_log = (const float*)d_in[5];
    char* wsb = (char*)d_ws;
    float* out = (float*)d_out;

    prep_conv_kernel<<<(MM + CC) / 4, 256, 0, stream>>>(X, Y, curv_log, ta_log, la_log, wsb);
    pos_kernel<<<MM / 4, 256, 0, stream>>>(X, Y, tgt, curv_log, wsb);
    main_kernel<<<NROWT * NCOLT, TPB, 0, stream>>>(tgt, wsb);
    final_kernel<<<MM / 256, 256, 0, stream>>>(wsb, curv_log, out);
}